// Round 15
// baseline (556.901 us; speedup 1.0000x reference)
//
#include <hip/hip_runtime.h>
#include <math.h>

#define Nn   100000
#define Ee   1600000
#define FIN  128
#define DIM  64
#define NCL  40
#define NHE  50000

#define CAPN 48
#define CAPH 80

#define FILLB 2048                 // fill blocks per side
#define NG1   ((Nn + 63) / 64)     // gemm1 blocks = 1563
#define NHEB  ((NHE + 3) / 4)      // gather_he blocks = 12500
#define XS_LD 132                  // xs tile row stride (ushorts)

typedef int iv4 __attribute__((ext_vector_type(4)));
typedef unsigned short ushort_t;
typedef unsigned char uchar_t;

__device__ __forceinline__ iv4 nt_load4(const int* p) {
    return __builtin_nontemporal_load((const iv4*)p);
}
__device__ __forceinline__ float bf2f(unsigned int h) { return __uint_as_float(h << 16); }
__device__ __forceinline__ ushort_t f2bf(float f) {
    unsigned int u = __float_as_uint(f);
    return (ushort_t)((u + 0x7fffu + ((u >> 16) & 1u)) >> 16);
}

// ---- fp8 e4m3fn manual encode (RNE) / decode ----
__device__ __forceinline__ uchar_t f2fp8(float f) {
    unsigned int u = __float_as_uint(f);
    unsigned int s = (u >> 24) & 0x80u;
    unsigned int a = u & 0x7fffffffu;
    if (a >= 0x43E00000u) return (uchar_t)(s | 0x7Eu);       // clamp to 448
    if (a < 0x3C800000u) {                                   // |v| < 2^-6: subnormal
        float af = __uint_as_float(a);
        unsigned int m = (unsigned int)(af * 512.f + 0.5f);  // round(v * 2^9)
        return (uchar_t)(s | m);                             // m<=8; m==8 -> normal min
    }
    unsigned int mant20 = a & 0xFFFFFu;
    unsigned int base = a >> 20;                             // exp8 | man3
    if (mant20 > 0x80000u || (mant20 == 0x80000u && (base & 1u))) base += 1u;
    unsigned int e = base >> 3;
    unsigned int m3 = base & 7u;
    int e8 = (int)e - 120;                                   // -127 + 7
    if (e8 >= 16) return (uchar_t)(s | 0x7Eu);
    return (uchar_t)(s | ((unsigned int)e8 << 3) | m3);
}
__device__ __forceinline__ float fp82f(unsigned int b) {
    unsigned int em = b & 0x7fu;
    float v;
    if (em >= 8u) v = __uint_as_float((((em >> 3) + 120u) << 23) | ((em & 7u) << 20));
    else          v = (float)em * 0.001953125f;              // 2^-9
    return (b & 0x80u) ? -v : v;
}

// ============ MEGA1: fill_h ∥ gemm1(fp8 out) ∥ wfuse ======================
__global__ __launch_bounds__(256) void mega1_k(
    const int* __restrict__ hn, const int* __restrict__ he,
    int* __restrict__ curH, int* __restrict__ adjH,
    const float* __restrict__ x, const float* __restrict__ W1,
    uchar_t* __restrict__ xw1,
    const float* __restrict__ Wh2, const float* __restrict__ bh2,
    const float* __restrict__ Wv2, const float* __restrict__ bv2,
    const float* __restrict__ Wo2, const float* __restrict__ bo2,
    float* __restrict__ Wh2f, float* __restrict__ b2f) {

    __shared__ __align__(16) unsigned char smem[FIN * DIM * 2 + 64 * XS_LD * 2]; // 33.3 KB
    const int bi = blockIdx.x;
    const int tid = threadIdx.x;

    if (bi < FILLB) {
        // ---------------- fill_h path ----------------
        const int cls = bi & 7;
        const int hlo = cls * (NHE / 8), hhi = hlo + (NHE / 8);
        const int cls_threads = (FILLB >> 3) * 256;
        const int t = (bi >> 3) * 256 + tid;
        for (int i0 = t * 4; i0 < Ee; i0 += cls_threads * 4) {
            int n0, n1, n2, n3, h0, h1, h2, h3;
            if (i0 + 3 < Ee) {
                iv4 nn = nt_load4(hn + i0);
                iv4 hh = nt_load4(he + i0);
                n0 = nn.x; n1 = nn.y; n2 = nn.z; n3 = nn.w;
                h0 = hh.x; h1 = hh.y; h2 = hh.z; h3 = hh.w;
            } else {
                n0 = hn[i0]; h0 = he[i0];
                n1 = (i0 + 1 < Ee) ? hn[i0 + 1] : 0; h1 = (i0 + 1 < Ee) ? he[i0 + 1] : -1;
                n2 = (i0 + 2 < Ee) ? hn[i0 + 2] : 0; h2 = (i0 + 2 < Ee) ? he[i0 + 2] : -1;
                n3 = (i0 + 3 < Ee) ? hn[i0 + 3] : 0; h3 = (i0 + 3 < Ee) ? he[i0 + 3] : -1;
            }
            if (h0 >= hlo && h0 < hhi) { int r = atomicAdd(&curH[h0], 1); if (r < CAPH) adjH[(size_t)h0 * CAPH + r] = n0; }
            if (h1 >= hlo && h1 < hhi) { int r = atomicAdd(&curH[h1], 1); if (r < CAPH) adjH[(size_t)h1 * CAPH + r] = n1; }
            if (h2 >= hlo && h2 < hhi) { int r = atomicAdd(&curH[h2], 1); if (r < CAPH) adjH[(size_t)h2 * CAPH + r] = n2; }
            if (h3 >= hlo && h3 < hhi) { int r = atomicAdd(&curH[h3], 1); if (r < CAPH) adjH[(size_t)h3 * CAPH + r] = n3; }
        }
    } else if (bi < FILLB + NG1) {
        // ---------------- gemm1 path: bf16 W + bf16 x tile in LDS ---------
        ushort_t* WsB = (ushort_t*)smem;                       // 16 KB
        ushort_t* xsB = (ushort_t*)(smem + FIN * DIM * 2);     // 16.9 KB
        int row0 = (bi - FILLB) * 64;
        for (int idx = tid; idx < FIN * DIM / 4; idx += 256) {
            float4 v = *(const float4*)&W1[idx * 4];
            ushort4 u;
            u.x = f2bf(v.x); u.y = f2bf(v.y); u.z = f2bf(v.z); u.w = f2bf(v.w);
            *(ushort4*)&WsB[idx * 4] = u;
        }
        for (int idx = tid; idx < 64 * 32; idx += 256) {
            int r = idx >> 5, kq = idx & 31;
            int row = row0 + r;
            ushort4 u = make_ushort4(0, 0, 0, 0);
            if (row < Nn) {
                float4 v = *(const float4*)&x[(size_t)row * FIN + kq * 4];
                u.x = f2bf(v.x); u.y = f2bf(v.y); u.z = f2bf(v.z); u.w = f2bf(v.w);
            }
            *(ushort4*)&xsB[r * XS_LD + kq * 4] = u;
        }
        __syncthreads();
        int tc = tid & 15, tr = tid >> 4;
        float acc[4][4] = {{0.f}};
#pragma unroll 2
        for (int k = 0; k < FIN; k += 2) {
            unsigned int xp0 = *(const unsigned int*)&xsB[(4 * tr + 0) * XS_LD + k];
            unsigned int xp1 = *(const unsigned int*)&xsB[(4 * tr + 1) * XS_LD + k];
            unsigned int xp2 = *(const unsigned int*)&xsB[(4 * tr + 2) * XS_LD + k];
            unsigned int xp3 = *(const unsigned int*)&xsB[(4 * tr + 3) * XS_LD + k];
            uint2 wp0 = *(const uint2*)&WsB[k * DIM + 4 * tc];
            uint2 wp1 = *(const uint2*)&WsB[(k + 1) * DIM + 4 * tc];
            float w00 = bf2f(wp0.x & 0xffffu), w01 = bf2f(wp0.x >> 16);
            float w02 = bf2f(wp0.y & 0xffffu), w03 = bf2f(wp0.y >> 16);
            float w10 = bf2f(wp1.x & 0xffffu), w11 = bf2f(wp1.x >> 16);
            float w12 = bf2f(wp1.y & 0xffffu), w13 = bf2f(wp1.y >> 16);
            float xa0 = bf2f(xp0 & 0xffffu), xb0 = bf2f(xp0 >> 16);
            float xa1 = bf2f(xp1 & 0xffffu), xb1 = bf2f(xp1 >> 16);
            float xa2 = bf2f(xp2 & 0xffffu), xb2 = bf2f(xp2 >> 16);
            float xa3 = bf2f(xp3 & 0xffffu), xb3 = bf2f(xp3 >> 16);
            acc[0][0] = fmaf(xa0, w00, fmaf(xb0, w10, acc[0][0]));
            acc[0][1] = fmaf(xa0, w01, fmaf(xb0, w11, acc[0][1]));
            acc[0][2] = fmaf(xa0, w02, fmaf(xb0, w12, acc[0][2]));
            acc[0][3] = fmaf(xa0, w03, fmaf(xb0, w13, acc[0][3]));
            acc[1][0] = fmaf(xa1, w00, fmaf(xb1, w10, acc[1][0]));
            acc[1][1] = fmaf(xa1, w01, fmaf(xb1, w11, acc[1][1]));
            acc[1][2] = fmaf(xa1, w02, fmaf(xb1, w12, acc[1][2]));
            acc[1][3] = fmaf(xa1, w03, fmaf(xb1, w13, acc[1][3]));
            acc[2][0] = fmaf(xa2, w00, fmaf(xb2, w10, acc[2][0]));
            acc[2][1] = fmaf(xa2, w01, fmaf(xb2, w11, acc[2][1]));
            acc[2][2] = fmaf(xa2, w02, fmaf(xb2, w12, acc[2][2]));
            acc[2][3] = fmaf(xa2, w03, fmaf(xb2, w13, acc[2][3]));
            acc[3][0] = fmaf(xa3, w00, fmaf(xb3, w10, acc[3][0]));
            acc[3][1] = fmaf(xa3, w01, fmaf(xb3, w11, acc[3][1]));
            acc[3][2] = fmaf(xa3, w02, fmaf(xb3, w12, acc[3][2]));
            acc[3][3] = fmaf(xa3, w03, fmaf(xb3, w13, acc[3][3]));
        }
#pragma unroll
        for (int i = 0; i < 4; ++i) {
            int row = row0 + 4 * tr + i;
            if (row < Nn) {
                uchar4 o;
                o.x = f2fp8(acc[i][0]); o.y = f2fp8(acc[i][1]);
                o.z = f2fp8(acc[i][2]); o.w = f2fp8(acc[i][3]);
                *(uchar4*)&xw1[(size_t)row * DIM + 4 * tc] = o;
            }
        }
    } else {
        // ---------------- wfuse path ----------------
        float* Wf = (float*)smem;
        float* bfv = (float*)(smem + NCL * NCL * 4);
        for (int idx = tid; idx < NCL * NCL; idx += 256) {
            int i = idx / NCL, j = idx - i * NCL;
            float a = 0.f;
#pragma unroll
            for (int k = 0; k < NCL; ++k) a = fmaf(Wv2[i * NCL + k], Wo2[k * NCL + j], a);
            Wf[idx] = a;
        }
        if (tid < NCL) {
            float a = bo2[tid];
#pragma unroll
            for (int k = 0; k < NCL; ++k) a = fmaf(bv2[k], Wo2[k * NCL + tid], a);
            bfv[tid] = a;
        }
        __syncthreads();
        for (int idx = tid; idx < DIM * NCL; idx += 256) {
            int i = idx / NCL, j = idx - i * NCL;
            float a = 0.f;
#pragma unroll
            for (int k = 0; k < NCL; ++k) a = fmaf(Wh2[i * NCL + k], Wf[k * NCL + j], a);
            Wh2f[idx] = a;
        }
        if (tid < NCL) {
            float a = bfv[tid];
#pragma unroll
            for (int k = 0; k < NCL; ++k) a = fmaf(bh2[k], Wf[k * NCL + tid], a);
            b2f[tid] = a;
        }
    }
}

// ============ MEGA2: fill_n ∥ gather_he<64> (fp8 in, bf16 out) =============
__global__ __launch_bounds__(256) void mega2_k(
    const int* __restrict__ hn, const int* __restrict__ he,
    int* __restrict__ curN, ushort_t* __restrict__ adjN,
    const uchar_t* __restrict__ xw, const int* __restrict__ curH,
    const int* __restrict__ adjH, ushort_t* __restrict__ me) {

    const int bi = blockIdx.x;
    const int tid = threadIdx.x;

    if (bi < FILLB) {
        // ---------------- fill_n path ----------------
        const int cls = bi & 7;
        const int nlo = cls * (Nn / 8), nhi = nlo + (Nn / 8);
        const int cls_threads = (FILLB >> 3) * 256;
        const int t = (bi >> 3) * 256 + tid;
        for (int i0 = t * 4; i0 < Ee; i0 += cls_threads * 4) {
            int n0, n1, n2, n3, h0, h1, h2, h3;
            if (i0 + 3 < Ee) {
                iv4 nn = nt_load4(hn + i0);
                iv4 hh = nt_load4(he + i0);
                n0 = nn.x; n1 = nn.y; n2 = nn.z; n3 = nn.w;
                h0 = hh.x; h1 = hh.y; h2 = hh.z; h3 = hh.w;
            } else {
                n0 = hn[i0]; h0 = he[i0];
                n1 = (i0 + 1 < Ee) ? hn[i0 + 1] : -1; h1 = (i0 + 1 < Ee) ? he[i0 + 1] : 0;
                n2 = (i0 + 2 < Ee) ? hn[i0 + 2] : -1; h2 = (i0 + 2 < Ee) ? he[i0 + 2] : 0;
                n3 = (i0 + 3 < Ee) ? hn[i0 + 3] : -1; h3 = (i0 + 3 < Ee) ? he[i0 + 3] : 0;
            }
            if (n0 >= nlo && n0 < nhi) { int r = atomicAdd(&curN[n0], 1); if (r < CAPN) adjN[(size_t)n0 * CAPN + r] = (ushort_t)h0; }
            if (n1 >= nlo && n1 < nhi) { int r = atomicAdd(&curN[n1], 1); if (r < CAPN) adjN[(size_t)n1 * CAPN + r] = (ushort_t)h1; }
            if (n2 >= nlo && n2 < nhi) { int r = atomicAdd(&curN[n2], 1); if (r < CAPN) adjN[(size_t)n2 * CAPN + r] = (ushort_t)h2; }
            if (n3 >= nlo && n3 < nhi) { int r = atomicAdd(&curN[n3], 1); if (r < CAPN) adjN[(size_t)n3 * CAPN + r] = (ushort_t)h3; }
        }
    } else {
        // ---------------- gather_he<64> path (fp8 rows) ----------------
        int h = (bi - FILLB) * 4 + (tid >> 6);
        int f = tid & 63;
        if (h >= NHE) return;
        int deg = curH[h];
        int cnt = deg < CAPH ? deg : CAPH;
        size_t lo = (size_t)h * CAPH;
        float a0 = 0.f, a1 = 0.f, a2 = 0.f, a3 = 0.f;
        float a4 = 0.f, a5 = 0.f, a6 = 0.f, a7 = 0.f;
        int j = 0;
        for (; j + 7 < cnt; j += 8) {
            int n0 = __builtin_nontemporal_load(adjH + lo + j);
            int n1 = __builtin_nontemporal_load(adjH + lo + j + 1);
            int n2 = __builtin_nontemporal_load(adjH + lo + j + 2);
            int n3 = __builtin_nontemporal_load(adjH + lo + j + 3);
            int n4 = __builtin_nontemporal_load(adjH + lo + j + 4);
            int n5 = __builtin_nontemporal_load(adjH + lo + j + 5);
            int n6 = __builtin_nontemporal_load(adjH + lo + j + 6);
            int n7 = __builtin_nontemporal_load(adjH + lo + j + 7);
            a0 += fp82f(xw[(size_t)n0 * DIM + f]);
            a1 += fp82f(xw[(size_t)n1 * DIM + f]);
            a2 += fp82f(xw[(size_t)n2 * DIM + f]);
            a3 += fp82f(xw[(size_t)n3 * DIM + f]);
            a4 += fp82f(xw[(size_t)n4 * DIM + f]);
            a5 += fp82f(xw[(size_t)n5 * DIM + f]);
            a6 += fp82f(xw[(size_t)n6 * DIM + f]);
            a7 += fp82f(xw[(size_t)n7 * DIM + f]);
        }
        for (; j < cnt; ++j) a0 += fp82f(xw[(size_t)__builtin_nontemporal_load(adjH + lo + j) * DIM + f]);
        float binv = deg > 0 ? 1.0f / (float)deg : 0.f;
        float s = ((a0 + a1) + (a2 + a3)) + ((a4 + a5) + (a6 + a7));
        me[(size_t)h * DIM + f] = f2bf(s * binv);
    }
}

// -------- gather: hyperedge side layer 2 (bf16 in/out) ---------------------
__global__ __launch_bounds__(256) void gather_he2(const ushort_t* __restrict__ xw,
                                                  const int* __restrict__ curH,
                                                  const int* __restrict__ adj,
                                                  ushort_t* __restrict__ me) {
    int h = blockIdx.x * 4 + (threadIdx.x >> 6);
    int f = threadIdx.x & 63;
    if (h >= NHE || f >= NCL) return;
    int deg = curH[h];
    int cnt = deg < CAPH ? deg : CAPH;
    size_t lo = (size_t)h * CAPH;
    float a0 = 0.f, a1 = 0.f, a2 = 0.f, a3 = 0.f;
    float a4 = 0.f, a5 = 0.f, a6 = 0.f, a7 = 0.f;
    int j = 0;
    for (; j + 7 < cnt; j += 8) {
        int n0 = __builtin_nontemporal_load(adj + lo + j);
        int n1 = __builtin_nontemporal_load(adj + lo + j + 1);
        int n2 = __builtin_nontemporal_load(adj + lo + j + 2);
        int n3 = __builtin_nontemporal_load(adj + lo + j + 3);
        int n4 = __builtin_nontemporal_load(adj + lo + j + 4);
        int n5 = __builtin_nontemporal_load(adj + lo + j + 5);
        int n6 = __builtin_nontemporal_load(adj + lo + j + 6);
        int n7 = __builtin_nontemporal_load(adj + lo + j + 7);
        a0 += bf2f(xw[(size_t)n0 * NCL + f]);
        a1 += bf2f(xw[(size_t)n1 * NCL + f]);
        a2 += bf2f(xw[(size_t)n2 * NCL + f]);
        a3 += bf2f(xw[(size_t)n3 * NCL + f]);
        a4 += bf2f(xw[(size_t)n4 * NCL + f]);
        a5 += bf2f(xw[(size_t)n5 * NCL + f]);
        a6 += bf2f(xw[(size_t)n6 * NCL + f]);
        a7 += bf2f(xw[(size_t)n7 * NCL + f]);
    }
    for (; j < cnt; ++j) a0 += bf2f(xw[(size_t)__builtin_nontemporal_load(adj + lo + j) * NCL + f]);
    float binv = deg > 0 ? 1.0f / (float)deg : 0.f;
    float s = ((a0 + a1) + (a2 + a3)) + ((a4 + a5) + (a6 + a7));
    me[(size_t)h * NCL + f] = f2bf(s * binv);
}

// ------- fused gather_n1 + gemm2 -------------------------------------------
__global__ __launch_bounds__(256) void gather_n1_g2(const ushort_t* __restrict__ me,
                                                    const int* __restrict__ curN,
                                                    const ushort_t* __restrict__ adj,
                                                    const float* __restrict__ bias,
                                                    const float* __restrict__ Wh2f,
                                                    ushort_t* __restrict__ xw2) {
    __shared__ float Wls[DIM * NCL];   // 10.2 KB
    __shared__ float xrow[4][DIM];     // 1 KB
    int tid = threadIdx.x;
    for (int i = tid; i < DIM * NCL; i += 256) Wls[i] = Wh2f[i];
    int wv = tid >> 6, f = tid & 63;
    int n = blockIdx.x * 4 + wv;
    bool valid = (n < Nn);
    float v = 0.f;
    if (valid) {
        int deg = curN[n];
        int cnt = deg < CAPN ? deg : CAPN;
        size_t lo = (size_t)n * CAPN;
        float a0 = 0.f, a1 = 0.f, a2 = 0.f, a3 = 0.f;
        float a4 = 0.f, a5 = 0.f, a6 = 0.f, a7 = 0.f;
        int j = 0;
        for (; j + 7 < cnt; j += 8) {
            int h0 = __builtin_nontemporal_load(adj + lo + j);
            int h1 = __builtin_nontemporal_load(adj + lo + j + 1);
            int h2 = __builtin_nontemporal_load(adj + lo + j + 2);
            int h3 = __builtin_nontemporal_load(adj + lo + j + 3);
            int h4 = __builtin_nontemporal_load(adj + lo + j + 4);
            int h5 = __builtin_nontemporal_load(adj + lo + j + 5);
            int h6 = __builtin_nontemporal_load(adj + lo + j + 6);
            int h7 = __builtin_nontemporal_load(adj + lo + j + 7);
            a0 += bf2f(me[(size_t)h0 * DIM + f]);
            a1 += bf2f(me[(size_t)h1 * DIM + f]);
            a2 += bf2f(me[(size_t)h2 * DIM + f]);
            a3 += bf2f(me[(size_t)h3 * DIM + f]);
            a4 += bf2f(me[(size_t)h4 * DIM + f]);
            a5 += bf2f(me[(size_t)h5 * DIM + f]);
            a6 += bf2f(me[(size_t)h6 * DIM + f]);
            a7 += bf2f(me[(size_t)h7 * DIM + f]);
        }
        for (; j < cnt; ++j) a0 += bf2f(me[(size_t)__builtin_nontemporal_load(adj + lo + j) * DIM + f]);
        float dinv = deg > 0 ? 1.0f / (float)deg : 0.f;
        float s = ((a0 + a1) + (a2 + a3)) + ((a4 + a5) + (a6 + a7));
        v = fmaxf(s * dinv + bias[f], 0.f);
    }
    xrow[wv][f] = v;
    __syncthreads();
    if (valid && f < NCL) {
        float acc = 0.f;
#pragma unroll
        for (int k = 0; k < DIM; ++k) acc = fmaf(xrow[wv][k], Wls[k * NCL + f], acc);
        xw2[(size_t)n * NCL + f] = f2bf(acc);
    }
}

// ------- gather node, layer 2 + log_softmax --------------------------------
__global__ __launch_bounds__(256) void gather_n2_sm(const ushort_t* __restrict__ me,
                                                    const int* __restrict__ curN,
                                                    const ushort_t* __restrict__ adj,
                                                    const float* __restrict__ b2f,
                                                    float* __restrict__ out) {
    int n = blockIdx.x * 4 + (threadIdx.x >> 6);
    int f = threadIdx.x & 63;
    if (n >= Nn) return;
    int deg = curN[n];
    int cnt = deg < CAPN ? deg : CAPN;
    size_t lo = (size_t)n * CAPN;
    float a0 = 0.f, a1 = 0.f, a2 = 0.f, a3 = 0.f;
    float a4 = 0.f, a5 = 0.f, a6 = 0.f, a7 = 0.f;
    if (f < NCL) {
        int j = 0;
        for (; j + 7 < cnt; j += 8) {
            int h0 = __builtin_nontemporal_load(adj + lo + j);
            int h1 = __builtin_nontemporal_load(adj + lo + j + 1);
            int h2 = __builtin_nontemporal_load(adj + lo + j + 2);
            int h3 = __builtin_nontemporal_load(adj + lo + j + 3);
            int h4 = __builtin_nontemporal_load(adj + lo + j + 4);
            int h5 = __builtin_nontemporal_load(adj + lo + j + 5);
            int h6 = __builtin_nontemporal_load(adj + lo + j + 6);
            int h7 = __builtin_nontemporal_load(adj + lo + j + 7);
            a0 += bf2f(me[(size_t)h0 * NCL + f]);
            a1 += bf2f(me[(size_t)h1 * NCL + f]);
            a2 += bf2f(me[(size_t)h2 * NCL + f]);
            a3 += bf2f(me[(size_t)h3 * NCL + f]);
            a4 += bf2f(me[(size_t)h4 * NCL + f]);
            a5 += bf2f(me[(size_t)h5 * NCL + f]);
            a6 += bf2f(me[(size_t)h6 * NCL + f]);
            a7 += bf2f(me[(size_t)h7 * NCL + f]);
        }
        for (; j < cnt; ++j) a0 += bf2f(me[(size_t)__builtin_nontemporal_load(adj + lo + j) * NCL + f]);
    }
    float dinv = deg > 0 ? 1.0f / (float)deg : 0.f;
    float s8 = ((a0 + a1) + (a2 + a3)) + ((a4 + a5) + (a6 + a7));
    float o = (f < NCL) ? s8 * dinv + b2f[f] : -INFINITY;
    float m = o;
#pragma unroll
    for (int off = 32; off >= 1; off >>= 1) m = fmaxf(m, __shfl_xor(m, off));
    float ex = (f < NCL) ? expf(o - m) : 0.f;
    float s = ex;
#pragma unroll
    for (int off = 32; off >= 1; off >>= 1) s += __shfl_xor(s, off);
    if (f < NCL) out[(size_t)n * NCL + f] = o - m - logf(s);
}

extern "C" void kernel_launch(void* const* d_in, const int* in_sizes, int n_in,
                              void* d_out, int out_size, void* d_ws, size_t ws_size,
                              hipStream_t stream) {
    (void)in_sizes; (void)n_in; (void)out_size; (void)ws_size;

    const float* x   = (const float*)d_in[0];
    const int*   hn  = (const int*)d_in[2];
    const int*   he  = (const int*)d_in[3];
    const float* Wh1 = (const float*)d_in[6];
    const float* bh1 = (const float*)d_in[7];
    const float* Wh2 = (const float*)d_in[18];
    const float* bh2 = (const float*)d_in[19];
    const float* Wv2 = (const float*)d_in[24];
    const float* bv2 = (const float*)d_in[25];
    const float* Wo2 = (const float*)d_in[26];
    const float* bo2 = (const float*)d_in[27];
    float* out = (float*)d_out;

    // ---- workspace layout ----
    uchar_t*  A8 = (uchar_t*)d_ws;                      // N*64 fp8 : xw1 (6.4 MB)
    ushort_t* A2 = (ushort_t*)(A8 + (size_t)Nn * DIM);  // N*40 bf16 : xw2 (8 MB)
    ushort_t* B  = A2 + (size_t)Nn * NCL;               // NHE*64 bf16 : m_e1 (6.4 MB)
    ushort_t* C  = B + (size_t)NHE * DIM;               // NHE*40 bf16 : m_e2 (4 MB)
    int* curN = (int*)(C + (size_t)NHE * NCL);          // N
    int* curH = curN + Nn;                              // NHE
    ushort_t* adjN = (ushort_t*)(curH + NHE);           // N*CAPN
    int* adjH = (int*)(adjN + (size_t)Nn * CAPN);       // NHE*CAPH
    float* Wh2f = (float*)(adjH + (size_t)NHE * CAPH);  // 64*40
    float* b2f  = Wh2f + DIM * NCL;                     // 40

    // ---- launch 1: zero cursors ----
    (void)hipMemsetAsync(curN, 0, (size_t)(Nn + NHE) * sizeof(int), stream);

    // ---- launch 2: fill_h ∥ gemm1 ∥ wfuse ----
    mega1_k<<<FILLB + NG1 + 1, 256, 0, stream>>>(hn, he, curH, adjH, x, Wh1, A8,
                                                 Wh2, bh2, Wv2, bv2, Wo2, bo2, Wh2f, b2f);

    // ---- launch 3: fill_n ∥ gather_he<64> (fp8 xw1 -> bf16 m_e1) ----
    mega2_k<<<FILLB + NHEB, 256, 0, stream>>>(hn, he, curN, adjN, A8, curH, adjH, B);

    // ---- launch 4: node gather layer 1 + gemm2 fused (m_e1 -> xw2) ----
    gather_n1_g2<<<(Nn + 3) / 4, 256, 0, stream>>>(B, curN, adjN, bh1, Wh2f, A2);

    // ---- launch 5: hyperedge gather, layer 2 (xw2 -> m_e2) ----
    gather_he2<<<NHEB, 256, 0, stream>>>(A2, curH, adjH, C);

    // ---- launch 6: node gather layer 2 + log_softmax -> out ----
    gather_n2_sm<<<(Nn + 3) / 4, 256, 0, stream>>>(C, curN, adjN, b2f, out);
}

// Round 16
// 486.716 us; speedup vs baseline: 1.1442x; 1.1442x over previous
//
#include <hip/hip_runtime.h>
#include <math.h>

#define Nn   100000
#define Ee   1600000
#define FIN  128
#define DIM  64
#define NCL  40
#define NHE  50000

#define CAPN 48
#define CAPH 80

#define FILLB 2048                 // fill blocks
#define NG1   ((Nn + 63) / 64)     // gemm1 blocks = 1563
#define INTRL (2 * NG1)            // interleaved prefix (gemm+fill alternating)
#define XS_LD 132                  // xs tile row stride (ushorts)

typedef int iv4 __attribute__((ext_vector_type(4)));
typedef unsigned short ushort_t;

__device__ __forceinline__ iv4 nt_load4(const int* p) {
    return __builtin_nontemporal_load((const iv4*)p);
}
__device__ __forceinline__ float bf2f(unsigned int h) { return __uint_as_float(h << 16); }
__device__ __forceinline__ ushort_t f2bf(float f) {
    unsigned int u = __float_as_uint(f);
    return (ushort_t)((u + 0x7fffu + ((u >> 16) & 1u)) >> 16);
}

// ============ MEGA KERNEL: fill ∥ gemm1 ∥ wfuse (interleaved blocks) =======
__global__ __launch_bounds__(256) void mega_k(
    const int* __restrict__ hn, const int* __restrict__ he,
    int* __restrict__ curN, int* __restrict__ curH,
    ushort_t* __restrict__ adjN, int* __restrict__ adjH,
    const float* __restrict__ x, const float* __restrict__ W1,
    ushort_t* __restrict__ xw1,
    const float* __restrict__ Wh2, const float* __restrict__ bh2,
    const float* __restrict__ Wv2, const float* __restrict__ bv2,
    const float* __restrict__ Wo2, const float* __restrict__ bo2,
    float* __restrict__ Wh2f, float* __restrict__ b2f) {

    __shared__ __align__(16) unsigned char smem[FIN * DIM * 2 + 64 * XS_LD * 2]; // 33.3 KB
    const int bi = blockIdx.x;
    const int tid = threadIdx.x;

    int role;   // 0 = gemm, 1 = fill, 2 = wfuse
    int rb;     // role-local block index
    if (bi < INTRL) { role = bi & 1; rb = bi >> 1; }
    else if (bi < FILLB + NG1) { role = 1; rb = bi - NG1; }
    else { role = 2; rb = 0; }

    if (role == 1) {
        // ---------------- fill path (no LDS) ----------------
        const int cls = rb & 7;
        const int nlo = cls * (Nn / 8), nhi = nlo + (Nn / 8);
        const int hlo = cls * (NHE / 8), hhi = hlo + (NHE / 8);
        const int cls_threads = (FILLB >> 3) * 256;
        const int t = (rb >> 3) * 256 + tid;
        for (int i0 = t * 4; i0 < Ee; i0 += cls_threads * 4) {
            int n0, n1, n2, n3, h0, h1, h2, h3;
            if (i0 + 3 < Ee) {
                iv4 nn = nt_load4(hn + i0);
                iv4 hh = nt_load4(he + i0);
                n0 = nn.x; n1 = nn.y; n2 = nn.z; n3 = nn.w;
                h0 = hh.x; h1 = hh.y; h2 = hh.z; h3 = hh.w;
            } else {
                n0 = hn[i0]; h0 = he[i0];
                n1 = (i0 + 1 < Ee) ? hn[i0 + 1] : -1; h1 = (i0 + 1 < Ee) ? he[i0 + 1] : -1;
                n2 = (i0 + 2 < Ee) ? hn[i0 + 2] : -1; h2 = (i0 + 2 < Ee) ? he[i0 + 2] : -1;
                n3 = (i0 + 3 < Ee) ? hn[i0 + 3] : -1; h3 = (i0 + 3 < Ee) ? he[i0 + 3] : -1;
            }
            if (n0 >= nlo && n0 < nhi) { int r = atomicAdd(&curN[n0], 1); if (r < CAPN) adjN[(size_t)n0 * CAPN + r] = (ushort_t)h0; }
            if (n1 >= nlo && n1 < nhi) { int r = atomicAdd(&curN[n1], 1); if (r < CAPN) adjN[(size_t)n1 * CAPN + r] = (ushort_t)h1; }
            if (n2 >= nlo && n2 < nhi) { int r = atomicAdd(&curN[n2], 1); if (r < CAPN) adjN[(size_t)n2 * CAPN + r] = (ushort_t)h2; }
            if (n3 >= nlo && n3 < nhi) { int r = atomicAdd(&curN[n3], 1); if (r < CAPN) adjN[(size_t)n3 * CAPN + r] = (ushort_t)h3; }
            if (h0 >= hlo && h0 < hhi) { int r = atomicAdd(&curH[h0], 1); if (r < CAPH) adjH[(size_t)h0 * CAPH + r] = n0; }
            if (h1 >= hlo && h1 < hhi) { int r = atomicAdd(&curH[h1], 1); if (r < CAPH) adjH[(size_t)h1 * CAPH + r] = n1; }
            if (h2 >= hlo && h2 < hhi) { int r = atomicAdd(&curH[h2], 1); if (r < CAPH) adjH[(size_t)h2 * CAPH + r] = n2; }
            if (h3 >= hlo && h3 < hhi) { int r = atomicAdd(&curH[h3], 1); if (r < CAPH) adjH[(size_t)h3 * CAPH + r] = n3; }
        }
    } else if (role == 0) {
        // ---------------- gemm1 path: bf16 W + bf16 x tile in LDS ---------
        ushort_t* WsB = (ushort_t*)smem;                       // 16 KB
        ushort_t* xsB = (ushort_t*)(smem + FIN * DIM * 2);     // 16.9 KB
        int row0 = rb * 64;
        for (int idx = tid; idx < FIN * DIM / 4; idx += 256) {
            float4 v = *(const float4*)&W1[idx * 4];
            ushort4 u;
            u.x = f2bf(v.x); u.y = f2bf(v.y); u.z = f2bf(v.z); u.w = f2bf(v.w);
            *(ushort4*)&WsB[idx * 4] = u;
        }
        for (int idx = tid; idx < 64 * 32; idx += 256) {
            int r = idx >> 5, kq = idx & 31;
            int row = row0 + r;
            ushort4 u = make_ushort4(0, 0, 0, 0);
            if (row < Nn) {
                float4 v = *(const float4*)&x[(size_t)row * FIN + kq * 4];
                u.x = f2bf(v.x); u.y = f2bf(v.y); u.z = f2bf(v.z); u.w = f2bf(v.w);
            }
            *(ushort4*)&xsB[r * XS_LD + kq * 4] = u;
        }
        __syncthreads();
        int tc = tid & 15, tr = tid >> 4;
        float acc[4][4] = {{0.f}};
#pragma unroll 2
        for (int k = 0; k < FIN; k += 2) {
            unsigned int xp0 = *(const unsigned int*)&xsB[(4 * tr + 0) * XS_LD + k];
            unsigned int xp1 = *(const unsigned int*)&xsB[(4 * tr + 1) * XS_LD + k];
            unsigned int xp2 = *(const unsigned int*)&xsB[(4 * tr + 2) * XS_LD + k];
            unsigned int xp3 = *(const unsigned int*)&xsB[(4 * tr + 3) * XS_LD + k];
            uint2 wp0 = *(const uint2*)&WsB[k * DIM + 4 * tc];
            uint2 wp1 = *(const uint2*)&WsB[(k + 1) * DIM + 4 * tc];
            float w00 = bf2f(wp0.x & 0xffffu), w01 = bf2f(wp0.x >> 16);
            float w02 = bf2f(wp0.y & 0xffffu), w03 = bf2f(wp0.y >> 16);
            float w10 = bf2f(wp1.x & 0xffffu), w11 = bf2f(wp1.x >> 16);
            float w12 = bf2f(wp1.y & 0xffffu), w13 = bf2f(wp1.y >> 16);
            float xa0 = bf2f(xp0 & 0xffffu), xb0 = bf2f(xp0 >> 16);
            float xa1 = bf2f(xp1 & 0xffffu), xb1 = bf2f(xp1 >> 16);
            float xa2 = bf2f(xp2 & 0xffffu), xb2 = bf2f(xp2 >> 16);
            float xa3 = bf2f(xp3 & 0xffffu), xb3 = bf2f(xp3 >> 16);
            acc[0][0] = fmaf(xa0, w00, fmaf(xb0, w10, acc[0][0]));
            acc[0][1] = fmaf(xa0, w01, fmaf(xb0, w11, acc[0][1]));
            acc[0][2] = fmaf(xa0, w02, fmaf(xb0, w12, acc[0][2]));
            acc[0][3] = fmaf(xa0, w03, fmaf(xb0, w13, acc[0][3]));
            acc[1][0] = fmaf(xa1, w00, fmaf(xb1, w10, acc[1][0]));
            acc[1][1] = fmaf(xa1, w01, fmaf(xb1, w11, acc[1][1]));
            acc[1][2] = fmaf(xa1, w02, fmaf(xb1, w12, acc[1][2]));
            acc[1][3] = fmaf(xa1, w03, fmaf(xb1, w13, acc[1][3]));
            acc[2][0] = fmaf(xa2, w00, fmaf(xb2, w10, acc[2][0]));
            acc[2][1] = fmaf(xa2, w01, fmaf(xb2, w11, acc[2][1]));
            acc[2][2] = fmaf(xa2, w02, fmaf(xb2, w12, acc[2][2]));
            acc[2][3] = fmaf(xa2, w03, fmaf(xb2, w13, acc[2][3]));
            acc[3][0] = fmaf(xa3, w00, fmaf(xb3, w10, acc[3][0]));
            acc[3][1] = fmaf(xa3, w01, fmaf(xb3, w11, acc[3][1]));
            acc[3][2] = fmaf(xa3, w02, fmaf(xb3, w12, acc[3][2]));
            acc[3][3] = fmaf(xa3, w03, fmaf(xb3, w13, acc[3][3]));
        }
#pragma unroll
        for (int i = 0; i < 4; ++i) {
            int row = row0 + 4 * tr + i;
            if (row < Nn) {
                ushort4 o;
                o.x = f2bf(acc[i][0]); o.y = f2bf(acc[i][1]);
                o.z = f2bf(acc[i][2]); o.w = f2bf(acc[i][3]);
                *(ushort4*)&xw1[(size_t)row * DIM + 4 * tc] = o;
            }
        }
    } else {
        // ---------------- wfuse path ----------------
        float* Wf = (float*)smem;
        float* bfv = (float*)(smem + NCL * NCL * 4);
        for (int idx = tid; idx < NCL * NCL; idx += 256) {
            int i = idx / NCL, j = idx - i * NCL;
            float a = 0.f;
#pragma unroll
            for (int k = 0; k < NCL; ++k) a = fmaf(Wv2[i * NCL + k], Wo2[k * NCL + j], a);
            Wf[idx] = a;
        }
        if (tid < NCL) {
            float a = bo2[tid];
#pragma unroll
            for (int k = 0; k < NCL; ++k) a = fmaf(bv2[k], Wo2[k * NCL + tid], a);
            bfv[tid] = a;
        }
        __syncthreads();
        for (int idx = tid; idx < DIM * NCL; idx += 256) {
            int i = idx / NCL, j = idx - i * NCL;
            float a = 0.f;
#pragma unroll
            for (int k = 0; k < NCL; ++k) a = fmaf(Wh2[i * NCL + k], Wf[k * NCL + j], a);
            Wh2f[idx] = a;
        }
        if (tid < NCL) {
            float a = bfv[tid];
#pragma unroll
            for (int k = 0; k < NCL; ++k) a = fmaf(bh2[k], Wf[k * NCL + tid], a);
            b2f[tid] = a;
        }
    }
}

// -------- gather: hyperedge side (bf16 in/out), 8-deep ILP -----------------
template <int F>
__global__ __launch_bounds__(256) void gather_he(const ushort_t* __restrict__ xw,
                                                 const int* __restrict__ curH,
                                                 const int* __restrict__ adj,
                                                 ushort_t* __restrict__ me) {
    int h = blockIdx.x * 4 + (threadIdx.x >> 6);
    int f = threadIdx.x & 63;
    if (h >= NHE || f >= F) return;
    int deg = curH[h];
    int cnt = deg < CAPH ? deg : CAPH;
    size_t lo = (size_t)h * CAPH;
    float a0 = 0.f, a1 = 0.f, a2 = 0.f, a3 = 0.f;
    float a4 = 0.f, a5 = 0.f, a6 = 0.f, a7 = 0.f;
    int j = 0;
    for (; j + 7 < cnt; j += 8) {
        int n0 = __builtin_nontemporal_load(adj + lo + j);
        int n1 = __builtin_nontemporal_load(adj + lo + j + 1);
        int n2 = __builtin_nontemporal_load(adj + lo + j + 2);
        int n3 = __builtin_nontemporal_load(adj + lo + j + 3);
        int n4 = __builtin_nontemporal_load(adj + lo + j + 4);
        int n5 = __builtin_nontemporal_load(adj + lo + j + 5);
        int n6 = __builtin_nontemporal_load(adj + lo + j + 6);
        int n7 = __builtin_nontemporal_load(adj + lo + j + 7);
        a0 += bf2f(xw[(size_t)n0 * F + f]);
        a1 += bf2f(xw[(size_t)n1 * F + f]);
        a2 += bf2f(xw[(size_t)n2 * F + f]);
        a3 += bf2f(xw[(size_t)n3 * F + f]);
        a4 += bf2f(xw[(size_t)n4 * F + f]);
        a5 += bf2f(xw[(size_t)n5 * F + f]);
        a6 += bf2f(xw[(size_t)n6 * F + f]);
        a7 += bf2f(xw[(size_t)n7 * F + f]);
    }
    for (; j < cnt; ++j) a0 += bf2f(xw[(size_t)__builtin_nontemporal_load(adj + lo + j) * F + f]);
    float binv = deg > 0 ? 1.0f / (float)deg : 0.f;
    float s = ((a0 + a1) + (a2 + a3)) + ((a4 + a5) + (a6 + a7));
    me[(size_t)h * F + f] = f2bf(s * binv);
}

// ------- fused gather_n1 + gemm2, 8-deep ILP -------------------------------
__global__ __launch_bounds__(256) void gather_n1_g2(const ushort_t* __restrict__ me,
                                                    const int* __restrict__ curN,
                                                    const ushort_t* __restrict__ adj,
                                                    const float* __restrict__ bias,
                                                    const float* __restrict__ Wh2f,
                                                    ushort_t* __restrict__ xw2) {
    __shared__ float Wls[DIM * NCL];   // 10.2 KB
    __shared__ float xrow[4][DIM];     // 1 KB
    int tid = threadIdx.x;
    for (int i = tid; i < DIM * NCL; i += 256) Wls[i] = Wh2f[i];
    int wv = tid >> 6, f = tid & 63;
    int n = blockIdx.x * 4 + wv;
    bool valid = (n < Nn);
    float v = 0.f;
    if (valid) {
        int deg = curN[n];
        int cnt = deg < CAPN ? deg : CAPN;
        size_t lo = (size_t)n * CAPN;
        float a0 = 0.f, a1 = 0.f, a2 = 0.f, a3 = 0.f;
        float a4 = 0.f, a5 = 0.f, a6 = 0.f, a7 = 0.f;
        int j = 0;
        for (; j + 7 < cnt; j += 8) {
            int h0 = __builtin_nontemporal_load(adj + lo + j);
            int h1 = __builtin_nontemporal_load(adj + lo + j + 1);
            int h2 = __builtin_nontemporal_load(adj + lo + j + 2);
            int h3 = __builtin_nontemporal_load(adj + lo + j + 3);
            int h4 = __builtin_nontemporal_load(adj + lo + j + 4);
            int h5 = __builtin_nontemporal_load(adj + lo + j + 5);
            int h6 = __builtin_nontemporal_load(adj + lo + j + 6);
            int h7 = __builtin_nontemporal_load(adj + lo + j + 7);
            a0 += bf2f(me[(size_t)h0 * DIM + f]);
            a1 += bf2f(me[(size_t)h1 * DIM + f]);
            a2 += bf2f(me[(size_t)h2 * DIM + f]);
            a3 += bf2f(me[(size_t)h3 * DIM + f]);
            a4 += bf2f(me[(size_t)h4 * DIM + f]);
            a5 += bf2f(me[(size_t)h5 * DIM + f]);
            a6 += bf2f(me[(size_t)h6 * DIM + f]);
            a7 += bf2f(me[(size_t)h7 * DIM + f]);
        }
        for (; j < cnt; ++j) a0 += bf2f(me[(size_t)__builtin_nontemporal_load(adj + lo + j) * DIM + f]);
        float dinv = deg > 0 ? 1.0f / (float)deg : 0.f;
        float s = ((a0 + a1) + (a2 + a3)) + ((a4 + a5) + (a6 + a7));
        v = fmaxf(s * dinv + bias[f], 0.f);
    }
    xrow[wv][f] = v;
    __syncthreads();
    if (valid && f < NCL) {
        float acc = 0.f;
#pragma unroll
        for (int k = 0; k < DIM; ++k) acc = fmaf(xrow[wv][k], Wls[k * NCL + f], acc);
        xw2[(size_t)n * NCL + f] = f2bf(acc);
    }
}

// ------- gather node, layer 2 + log_softmax, 8-deep ILP --------------------
__global__ __launch_bounds__(256) void gather_n2_sm(const ushort_t* __restrict__ me,
                                                    const int* __restrict__ curN,
                                                    const ushort_t* __restrict__ adj,
                                                    const float* __restrict__ b2f,
                                                    float* __restrict__ out) {
    int n = blockIdx.x * 4 + (threadIdx.x >> 6);
    int f = threadIdx.x & 63;
    if (n >= Nn) return;
    int deg = curN[n];
    int cnt = deg < CAPN ? deg : CAPN;
    size_t lo = (size_t)n * CAPN;
    float a0 = 0.f, a1 = 0.f, a2 = 0.f, a3 = 0.f;
    float a4 = 0.f, a5 = 0.f, a6 = 0.f, a7 = 0.f;
    if (f < NCL) {
        int j = 0;
        for (; j + 7 < cnt; j += 8) {
            int h0 = __builtin_nontemporal_load(adj + lo + j);
            int h1 = __builtin_nontemporal_load(adj + lo + j + 1);
            int h2 = __builtin_nontemporal_load(adj + lo + j + 2);
            int h3 = __builtin_nontemporal_load(adj + lo + j + 3);
            int h4 = __builtin_nontemporal_load(adj + lo + j + 4);
            int h5 = __builtin_nontemporal_load(adj + lo + j + 5);
            int h6 = __builtin_nontemporal_load(adj + lo + j + 6);
            int h7 = __builtin_nontemporal_load(adj + lo + j + 7);
            a0 += bf2f(me[(size_t)h0 * NCL + f]);
            a1 += bf2f(me[(size_t)h1 * NCL + f]);
            a2 += bf2f(me[(size_t)h2 * NCL + f]);
            a3 += bf2f(me[(size_t)h3 * NCL + f]);
            a4 += bf2f(me[(size_t)h4 * NCL + f]);
            a5 += bf2f(me[(size_t)h5 * NCL + f]);
            a6 += bf2f(me[(size_t)h6 * NCL + f]);
            a7 += bf2f(me[(size_t)h7 * NCL + f]);
        }
        for (; j < cnt; ++j) a0 += bf2f(me[(size_t)__builtin_nontemporal_load(adj + lo + j) * NCL + f]);
    }
    float dinv = deg > 0 ? 1.0f / (float)deg : 0.f;
    float s8 = ((a0 + a1) + (a2 + a3)) + ((a4 + a5) + (a6 + a7));
    float o = (f < NCL) ? s8 * dinv + b2f[f] : -INFINITY;
    float m = o;
#pragma unroll
    for (int off = 32; off >= 1; off >>= 1) m = fmaxf(m, __shfl_xor(m, off));
    float ex = (f < NCL) ? expf(o - m) : 0.f;
    float s = ex;
#pragma unroll
    for (int off = 32; off >= 1; off >>= 1) s += __shfl_xor(s, off);
    if (f < NCL) out[(size_t)n * NCL + f] = o - m - logf(s);
}

extern "C" void kernel_launch(void* const* d_in, const int* in_sizes, int n_in,
                              void* d_out, int out_size, void* d_ws, size_t ws_size,
                              hipStream_t stream) {
    (void)in_sizes; (void)n_in; (void)out_size; (void)ws_size;

    const float* x   = (const float*)d_in[0];
    const int*   hn  = (const int*)d_in[2];
    const int*   he  = (const int*)d_in[3];
    const float* Wh1 = (const float*)d_in[6];
    const float* bh1 = (const float*)d_in[7];
    const float* Wh2 = (const float*)d_in[18];
    const float* bh2 = (const float*)d_in[19];
    const float* Wv2 = (const float*)d_in[24];
    const float* bv2 = (const float*)d_in[25];
    const float* Wo2 = (const float*)d_in[26];
    const float* bo2 = (const float*)d_in[27];
    float* out = (float*)d_out;

    // ---- workspace layout ----
    ushort_t* A = (ushort_t*)d_ws;                     // N*64 bf16 : xw1, then xw2 (N*40)
    ushort_t* B = A + (size_t)Nn * DIM;                // NHE*64 bf16 : m_e1
    ushort_t* C = B + (size_t)NHE * DIM;               // NHE*40 bf16 : m_e2
    int* curN = (int*)(C + (size_t)NHE * NCL);         // N
    int* curH = curN + Nn;                             // NHE
    ushort_t* adjN = (ushort_t*)(curH + NHE);          // N*CAPN
    int* adjH = (int*)(adjN + (size_t)Nn * CAPN);      // NHE*CAPH
    float* Wh2f = (float*)(adjH + (size_t)NHE * CAPH); // 64*40
    float* b2f  = Wh2f + DIM * NCL;                    // 40

    // ---- launch 1: zero cursors ----
    (void)hipMemsetAsync(curN, 0, (size_t)(Nn + NHE) * sizeof(int), stream);

    // ---- launch 2: fill ∥ gemm1 ∥ wfuse (interleaved) ----
    mega_k<<<FILLB + NG1 + 1, 256, 0, stream>>>(hn, he, curN, curH, adjN, adjH,
                                                x, Wh1, A,
                                                Wh2, bh2, Wv2, bv2, Wo2, bo2, Wh2f, b2f);

    // ---- launch 3: hyperedge gather, layer 1 (xw1 -> m_e1) ----
    gather_he<DIM><<<(NHE + 3) / 4, 256, 0, stream>>>(A, curH, adjH, B);

    // ---- launch 4: node gather layer 1 + gemm2 fused (m_e1 -> xw2) ----
    gather_n1_g2<<<(Nn + 3) / 4, 256, 0, stream>>>(B, curN, adjN, bh1, Wh2f, A);

    // ---- launch 5: hyperedge gather, layer 2 (xw2 -> m_e2) ----
    gather_he<NCL><<<(NHE + 3) / 4, 256, 0, stream>>>(A, curH, adjH, C);

    // ---- launch 6: node gather layer 2 + log_softmax -> out ----
    gather_n2_sm<<<(Nn + 3) / 4, 256, 0, stream>>>(C, curN, adjN, b2f, out);
}